// Round 12
// baseline (393.767 us; speedup 1.0000x reference)
//
#include <hip/hip_runtime.h>
#include <math.h>

#define NPTS 4096
#define BLK 256
#define V 32
#define NPROJ 256
#define NBATCH 32

// R18: polished two-wave-per-sort (v[32]) targeting OCCUPANCY, the only
// lever left. Series synthesis: VALU-busy time is ~210us in EVERY structure
// (R8 arch-resident 209; R12-R17 "shuttled" 206-223) => the class-split/
// shuttle theory is dead; busy-time is real work, dur = ~210us / busy%.
// busy% (53-63%) is wave starvation: v[64] variants are reg-bound at 13-16
// waves/CU. v[32] (this structure) is the only one that can reach 24-32.
// vs R16 (419us, 14 waves, 53% busy):
//  1. LDS 32->16 KiB: ONE buffer, sorts time-share -> 8 blocks/CU (32-wave
//     HW cap) instead of 5.
//  2. Fused m4096 round: rev(T^127) + cleaner j2048(T^64) in ONE LDS round
//     (1 write + 3 partner reads; partner64's rev recomputed in-reg:
//     keep(raw[T^64,r], raw[T^63,31-r], !w) — exactly what lane T^64
//     computes, so tie-handling matches). -8 ds_writes, -2 barriers/sort.
//  3. Overlap: x trips while y waits; y trips while x runs cleaner chunks
//     A/B; y cleans+publishes while x finishes C. 6 unconditional barriers.
// Network (verified R16, absmax 0.0): idx = T*32 + r, T=tid&127 (2 waves/
// sort), sortid=tid>>7 (0:x 1:y). merges 2..32 in-reg; 64..2048 in-wave
// (rev_shfl32<(m/32-1)> + stage_shfl chain + stages<16,1>); m4096 fused
// round + in-wave cleaners j=1024..32 + stages<16,1>.
// keep() = branchless compare-select. Publish slot (T<<3)|(c^(T&7)).

__device__ __forceinline__ void cmpex_asc(float& a, float& b) {
    const float lo = fminf(a, b), hi = fmaxf(a, b);
    a = lo; b = hi;
}

template<int JB, int JL>
__device__ __forceinline__ void stages(float* v) {
#pragma unroll
    for (int r = 0; r < V; ++r)
        if ((r & JB) == 0) cmpex_asc(v[r], v[r | JB]);
    if constexpr (JB > JL) stages<(JB >> 1), JL>(v);
}

template<int MASK>
__device__ __forceinline__ void rev_inreg(float* v) {
    constexpr int S = (MASK + 1) >> 1;
#pragma unroll
    for (int r = 0; r < V; ++r) {
        if ((r & S) == 0) {
            const float a = v[r], b = v[r ^ MASK];
            v[r] = fminf(a, b);
            v[r ^ MASK] = fmaxf(a, b);
        }
    }
}

// hi lanes keep max, lo keep min; ties keep `mine` on lo side, `q` on hi
// side — a consistent exchange (partners split the pair).
__device__ __forceinline__ float keep(float mine, float q, bool hi) {
    return ((q < mine) != hi) ? q : mine;
}

// Reversal across thread-pair (xor XM), registers reversed (r <-> 31-r).
template<int XM>
__device__ __forceinline__ void rev_shfl32(float* v, bool hi) {
#pragma unroll
    for (int r = 0; r < 16; ++r) {
        const float pa = __shfl_xor(v[31 - r], XM, 64);
        const float pb = __shfl_xor(v[r], XM, 64);
        v[r]      = keep(v[r],      pa, hi);
        v[31 - r] = keep(v[31 - r], pb, hi);
    }
}
// Same-register cross-thread stage (xor XM).
template<int XM>
__device__ __forceinline__ void stage_shfl(float* v, bool hi) {
#pragma unroll
    for (int r = 0; r < V; ++r) {
        const float q = __shfl_xor(v[r], XM, 64);
        v[r] = keep(v[r], q, hi);
    }
}

// Publish write, float4-slot = (T<<3)|(c^(T&7)): per instr the 64 lanes
// cover all 32 banks 8x (minimum for 1024B) — conflict-free family.
__device__ __forceinline__ void write_own(float* s, const float* v, int T) {
    float4* s4 = (float4*)s;
    const int tb = T & 7;
#pragma unroll
    for (int c = 0; c < 8; ++c)
        s4[(T << 3) | (c ^ tb)] =
            make_float4(v[4*c], v[4*c+1], v[4*c+2], v[4*c+3]);
}

// Fused m4096 rev (partner T^127, regs reversed, keep=w) + j=2048 cleaner
// (partner T^64, keep=w). Own raw values come from registers; three partner
// slot-reads reconstruct both exchange layers in one LDS round.
__device__ __forceinline__ void fused_trip(const float* s, float* v, int T, bool w) {
    const float4* s4 = (const float4*)s;
    const int tb = T & 7;
    const int pt127 = T ^ 127, pb127 = pt127 & 7;
    const int pt64  = T ^ 64;                 // (T^64)&7 == tb
    const int pt63  = T ^ 63,  pb63 = pt63 & 7;
#pragma unroll
    for (int c = 0; c < 8; ++c) {
        const float4 qr = s4[(pt127 << 3) | ((7 - c) ^ pb127)]; // rev partner (reg-reversed)
        const float4 q6 = s4[(pt64  << 3) | (c ^ tb)];          // j2048 partner raw
        const float4 q7 = s4[(pt63  << 3) | ((7 - c) ^ pb63)];  // its rev source
        // own rev result
        const float a0 = keep(v[4*c+0], qr.w, w);
        const float a1 = keep(v[4*c+1], qr.z, w);
        const float a2 = keep(v[4*c+2], qr.y, w);
        const float a3 = keep(v[4*c+3], qr.x, w);
        // partner T^64's rev result (its keep side is !w)
        const float b0 = keep(q6.x, q7.w, !w);
        const float b1 = keep(q6.y, q7.z, !w);
        const float b2 = keep(q6.z, q7.y, !w);
        const float b3 = keep(q6.w, q7.x, !w);
        // j2048 exchange
        v[4*c+0] = keep(a0, b0, w);
        v[4*c+1] = keep(a1, b1, w);
        v[4*c+2] = keep(a2, b2, w);
        v[4*c+3] = keep(a3, b3, w);
    }
}

// Load 32 points (96 floats = 24 float4) and project onto (p0,p1,p2).
__device__ __forceinline__ void load_project(const float* base, float* v,
                                             float p0, float p1, float p2) {
    const float4* b4 = (const float4*)base;
#pragma unroll
    for (int g = 0; g < 8; ++g) {
        float4 a = b4[g * 3 + 0], c = b4[g * 3 + 1], d = b4[g * 3 + 2];
        v[4*g+0] = a.x * p0 + a.y * p1 + a.z * p2;
        v[4*g+1] = a.w * p0 + c.x * p1 + c.y * p2;
        v[4*g+2] = c.z * p0 + c.w * p1 + d.x * p2;
        v[4*g+3] = d.y * p0 + d.z * p1 + d.w * p2;
    }
}

__global__ __launch_bounds__(BLK, 2) void swd_kernel(
    const float* __restrict__ x, const float* __restrict__ y,
    const float* __restrict__ theta, const float* __restrict__ rot,
    float* __restrict__ per_batch) {
    __shared__ float buf[NPTS];   // 16 KiB, time-shared by the two sorts

    const int tid = threadIdx.x;
    const int sortid = tid >> 7;          // 0: x (waves 0-1), 1: y (waves 2-3)
    const int T = tid & 127;              // thread-in-sort
    const int t = tid & 63;               // wave lane (= T & 63)
    const bool w = (T & 64) != 0;         // sort's wave half (idx bit 11)
    const int p = blockIdx.x;
    const int b = blockIdx.y;

    const float t0 = theta[p * 3 + 0], t1 = theta[p * 3 + 1], t2 = theta[p * 3 + 2];
    const float* R = rot + b * 9;
    const float p0 = t0 * R[0] + t1 * R[3] + t2 * R[6];
    const float p1 = t0 * R[1] + t1 * R[4] + t2 * R[7];
    const float p2 = t0 * R[2] + t1 * R[5] + t2 * R[8];

    const float* src = sortid ? y : x;

    float v[V];
    load_project(src + (size_t)b * NPTS * 3 + (size_t)T * V * 3, v, p0, p1, p2);

    const bool h1  = (t & 1) != 0;
    const bool h2  = (t & 2) != 0;
    const bool h4  = (t & 4) != 0;
    const bool h8  = (t & 8) != 0;
    const bool h16 = (t & 16) != 0;
    const bool h32 = (t & 32) != 0;

    // merges 2..32: in-reg
    rev_inreg<1>(v);
    rev_inreg<3>(v);  stages<1, 1>(v);
    rev_inreg<7>(v);  stages<2, 1>(v);
    rev_inreg<15>(v); stages<4, 1>(v);
    rev_inreg<31>(v); stages<8, 1>(v);
    // merge 64: rev T^1 (keep bit 5 = T bit 0)
    rev_shfl32<1>(v, h1);
    stages<16, 1>(v);
    // merge 128
    rev_shfl32<3>(v, h2);
    stage_shfl<1>(v, h1);
    stages<16, 1>(v);
    // merge 256
    rev_shfl32<7>(v, h4);
    stage_shfl<2>(v, h2);
    stage_shfl<1>(v, h1);
    stages<16, 1>(v);
    // merge 512
    rev_shfl32<15>(v, h8);
    stage_shfl<4>(v, h4);
    stage_shfl<2>(v, h2);
    stage_shfl<1>(v, h1);
    stages<16, 1>(v);
    // merge 1024
    rev_shfl32<31>(v, h16);
    stage_shfl<8>(v, h8);
    stage_shfl<4>(v, h4);
    stage_shfl<2>(v, h2);
    stage_shfl<1>(v, h1);
    stages<16, 1>(v);
    // merge 2048
    rev_shfl32<63>(v, h32);
    stage_shfl<16>(v, h16);
    stage_shfl<8>(v, h8);
    stage_shfl<4>(v, h4);
    stage_shfl<2>(v, h2);
    stage_shfl<1>(v, h1);
    stages<16, 1>(v);

    // ---- merge 4096: fused LDS round per sort, buffer time-shared.
    // Phase 1-2: x's round (y idles briefly).
    if (sortid == 0) write_own(buf, v, T);
    __syncthreads();
    if (sortid == 0) fused_trip(buf, v, T, w);
    __syncthreads();
    // Phase 3: y writes; x runs cleaner chunk A (j=1024, 512).
    if (sortid == 1) {
        write_own(buf, v, T);
    } else {
        stage_shfl<32>(v, h32);
        stage_shfl<16>(v, h16);
    }
    __syncthreads();
    // Phase 4: y fused-trip; x cleaner chunk B (j=256, 128).
    if (sortid == 1) {
        fused_trip(buf, v, T, w);
    } else {
        stage_shfl<8>(v, h8);
        stage_shfl<4>(v, h4);
    }
    __syncthreads();
    // Phase 5: y all cleaners + publish; x finishes chunk C.
    if (sortid == 1) {
        stage_shfl<32>(v, h32);
        stage_shfl<16>(v, h16);
        stage_shfl<8>(v, h8);
        stage_shfl<4>(v, h4);
        stage_shfl<2>(v, h2);
        stage_shfl<1>(v, h1);
        stages<16, 1>(v);
        write_own(buf, v, T);
    } else {
        stage_shfl<2>(v, h2);
        stage_shfl<1>(v, h1);
        stages<16, 1>(v);
    }
    __syncthreads();
    // Phase 6: x fused read+diff against published y.
    if (sortid == 0) {
        const float4* s4 = (const float4*)buf;
        const int tb = T & 7;
        float s = 0.0f;
#pragma unroll
        for (int c = 0; c < 8; ++c) {
            const float4 f = s4[(T << 3) | (c ^ tb)];
            const float d0 = v[4*c+0] - f.x;
            const float d1 = v[4*c+1] - f.y;
            const float d2 = v[4*c+2] - f.z;
            const float d3 = v[4*c+3] - f.w;
            s += d0 * d0 + d1 * d1 + d2 * d2 + d3 * d3;
        }
        for (int off = 32; off > 0; off >>= 1) s += __shfl_down(s, off, 64);
        if (t == 0) atomicAdd(&per_batch[b], s);   // one add per x-wave
    }
}

__global__ void finalize_kernel(const float* __restrict__ per_batch, float* __restrict__ out) {
    const int t = threadIdx.x;  // 64 threads
    float v = (t < NBATCH) ? sqrtf(per_batch[t] * (1.0f / (float)NPROJ)) : 0.0f;
    for (int off = 32; off > 0; off >>= 1) v += __shfl_down(v, off, 64);
    if (t == 0) out[0] = v * (1.0f / (float)NBATCH);
}

extern "C" void kernel_launch(void* const* d_in, const int* in_sizes, int n_in,
                              void* d_out, int out_size, void* d_ws, size_t ws_size,
                              hipStream_t stream) {
    const float* x = (const float*)d_in[0];
    const float* y = (const float*)d_in[1];
    const float* theta = (const float*)d_in[2];
    const float* rot = (const float*)d_in[3];
    float* per_batch = (float*)d_ws;
    float* out = (float*)d_out;

    hipMemsetAsync(per_batch, 0, NBATCH * sizeof(float), stream);

    dim3 grid(NPROJ, NBATCH);
    swd_kernel<<<grid, BLK, 0, stream>>>(x, y, theta, rot, per_batch);

    finalize_kernel<<<1, 64, 0, stream>>>(per_batch, out);
}

// Round 13
// 354.224 us; speedup vs baseline: 1.1116x; 1.1116x over previous
//
#include <hip/hip_runtime.h>
#include <math.h>

#define NPTS 4096
#define BLK 128
#define V 64
#define NPROJ 256
#define NBATCH 32

// R19 = R13 resubmission (best measured: 352.1us total, kernel 328-333us,
// passed, absmax 0.0). 12-round synthesis says this is the session plateau:
// VALU-busy time is ~210us in EVERY structure tried (LDS-heavy R8: 209,
// pure-shfl R13/R17: 206-208, two-wave v[32] R16/R18: 222-233); busy%
// saturates at 53-63% regardless of occupancy (32-55%) — latency-bound on
// shfl->select dependency chains; and the arch/acc register split is
// immovable (occupancy attrs, asm pins, sched_barrier, footprint halving
// all failed). Remaining micro-theories predict <10% with correctness risk;
// locking in the verified best instead.
// Structure: LDS-free shfl-bitonic sort, layout A (element idx = lane*64 +
// reg); merges 2..64 in-reg; merge m>=128: rev_shfl<(m-1)>>6> +
// stage_shfl<j>>6> (j=m/4..64) + stages<32,1> in-reg.
// keep() = branchless compare-select (v_cmp + s_xor_b64 lane-mask +
// v_cndmask). LDS = one 16 KiB publish buffer; wave 1 publishes sorted y,
// wave 0 does the fused read+diff. waves_per_eu(2,4) — R13's config.

__device__ __forceinline__ void cmpex_asc(float& a, float& b) {
    const float lo = fminf(a, b), hi = fmaxf(a, b);
    a = lo; b = hi;
}

template<int JB, int JL>
__device__ __forceinline__ void stages(float* v) {
#pragma unroll
    for (int r = 0; r < V; ++r)
        if ((r & JB) == 0) cmpex_asc(v[r], v[r | JB]);
    if constexpr (JB > JL) stages<(JB >> 1), JL>(v);
}

template<int MASK>
__device__ __forceinline__ void rev_inreg(float* v) {
    constexpr int S = (MASK + 1) >> 1;
#pragma unroll
    for (int r = 0; r < V; ++r) {
        if ((r & S) == 0) {
            const float a = v[r], b = v[r ^ MASK];
            v[r] = fminf(a, b);
            v[r ^ MASK] = fmaxf(a, b);
        }
    }
}

// Keep-side select: hi lanes keep max, lo lanes keep min, of (mine, q).
// ((q < mine) != hi) ? q : mine  ==  hi ? max : min   (ties keep mine).
// Lowers to v_cmp + s_xor_b64 (hi is a loop-invariant lane-mask) + v_cndmask.
__device__ __forceinline__ float keep(float mine, float q, bool hi) {
    return ((q < mine) != hi) ? q : mine;
}

// Reversal across thread-pair (xor XM), registers reversed (r <-> 63-r).
// Element (t, r) exchanges with (t^XM, 63-r); hi lanes keep max.
template<int XM>
__device__ __forceinline__ void rev_shfl(float* v, bool hi) {
#pragma unroll
    for (int r = 0; r < 32; ++r) {
        const float pa = __shfl_xor(v[63 - r], XM, 64);
        const float pb = __shfl_xor(v[r], XM, 64);
        v[r]      = keep(v[r],      pa, hi);
        v[63 - r] = keep(v[63 - r], pb, hi);
    }
}
// Same-register cross-thread stage (xor XM).
template<int XM>
__device__ __forceinline__ void stage_shfl(float* v, bool hi) {
#pragma unroll
    for (int r = 0; r < V; ++r) {
        const float q = __shfl_xor(v[r], XM, 64);
        v[r] = keep(v[r], q, hi);
    }
}

// Natural (own-slot) publish write, float4-slot = (t<<4)|(c^t15)
// (bank-spreading XOR placement: 2 lanes/bank per instr = conflict-free).
__device__ __forceinline__ void write_own(float* s, const float* v, int t, int t15) {
    float4* s4 = (float4*)s;
#pragma unroll
    for (int c = 0; c < 16; ++c)
        s4[(t << 4) | (c ^ t15)] =
            make_float4(v[4*c], v[4*c+1], v[4*c+2], v[4*c+3]);
}

__device__ __forceinline__ void load_project(const float* base, float* v,
                                             float p0, float p1, float p2) {
    const float4* b4 = (const float4*)base;
#pragma unroll
    for (int g = 0; g < 16; ++g) {
        float4 a = b4[g * 3 + 0], c = b4[g * 3 + 1], d = b4[g * 3 + 2];
        v[4*g+0] = a.x * p0 + a.y * p1 + a.z * p2;
        v[4*g+1] = a.w * p0 + c.x * p1 + c.y * p2;
        v[4*g+2] = c.z * p0 + c.w * p1 + d.x * p2;
        v[4*g+3] = d.y * p0 + d.z * p1 + d.w * p2;
    }
}

// Full ascending sort of 4096 floats held as v[64] per thread, layout A
// (element idx = t*64 + r). Pure in-register + cross-lane; no LDS.
__device__ __forceinline__ void sort4096(float* v, int t) {
    const bool hi1  = (t & 1) != 0;
    const bool hi2  = (t & 2) != 0;
    const bool hi4  = (t & 4) != 0;
    const bool hi8  = (t & 8) != 0;
    const bool hi16 = (t & 16) != 0;
    const bool hi32 = (t & 32) != 0;

    // merges 2..64: fully in-register
    rev_inreg<1>(v);
    rev_inreg<3>(v);  stages<1, 1>(v);
    rev_inreg<7>(v);  stages<2, 1>(v);
    rev_inreg<15>(v); stages<4, 1>(v);
    rev_inreg<31>(v); stages<8, 1>(v);
    rev_inreg<63>(v); stages<16, 1>(v);

    // merge 128
    rev_shfl<1>(v, hi1);
    stages<32, 1>(v);

    // merge 256
    rev_shfl<3>(v, hi2);
    stage_shfl<2>(v, hi2);
    stage_shfl<1>(v, hi1);
    stages<32, 1>(v);

    // merge 512
    rev_shfl<7>(v, hi4);
    stage_shfl<2>(v, hi2);
    stage_shfl<1>(v, hi1);
    stages<32, 1>(v);

    // merge 1024
    rev_shfl<15>(v, hi8);
    stage_shfl<4>(v, hi4);
    stage_shfl<2>(v, hi2);
    stage_shfl<1>(v, hi1);
    stages<32, 1>(v);

    // merge 2048
    rev_shfl<31>(v, hi16);
    stage_shfl<8>(v, hi8);
    stage_shfl<4>(v, hi4);
    stage_shfl<2>(v, hi2);
    stage_shfl<1>(v, hi1);
    stages<32, 1>(v);

    // merge 4096
    rev_shfl<63>(v, hi32);
    stage_shfl<16>(v, hi16);
    stage_shfl<8>(v, hi8);
    stage_shfl<4>(v, hi4);
    stage_shfl<2>(v, hi2);
    stage_shfl<1>(v, hi1);
    stages<32, 1>(v);
}

__global__ __launch_bounds__(BLK)
__attribute__((amdgpu_waves_per_eu(2, 4)))
void swd_kernel(
    const float* __restrict__ x, const float* __restrict__ y,
    const float* __restrict__ theta, const float* __restrict__ rot,
    float* __restrict__ per_batch) {
    __shared__ float buf[NPTS];   // 16 KiB — publish buffer only

    const int t = threadIdx.x & 63;       // wave lane
    const int wave = threadIdx.x >> 6;    // 0: x, 1: y
    const int p = blockIdx.x;
    const int b = blockIdx.y;

    const float t0 = theta[p * 3 + 0], t1 = theta[p * 3 + 1], t2 = theta[p * 3 + 2];
    const float* R = rot + b * 9;
    const float p0 = t0 * R[0] + t1 * R[3] + t2 * R[6];
    const float p1 = t0 * R[1] + t1 * R[4] + t2 * R[7];
    const float p2 = t0 * R[2] + t1 * R[5] + t2 * R[8];

    const float* src = wave ? y : x;

    // Each wave sorts its own array, completely barrier- and LDS-free.
    float v[V];
    load_project(src + (size_t)b * NPTS * 3 + (size_t)t * V * 3, v, p0, p1, p2);
    sort4096(v, t);

    const int t15 = t & 15;
    // Wave 1 publishes sorted y; wave 0 then diffs.
    if (wave == 1) write_own(buf, v, t, t15);
    __syncthreads();

    if (wave == 0) {
        // Fused read+diff: w never materializes (epilogue pressure ~v[64]+8).
        const float4* s4 = (const float4*)buf;
        float s = 0.0f;
#pragma unroll
        for (int c = 0; c < 16; ++c) {
            const float4 f = s4[(t << 4) | (c ^ t15)];
            const float d0 = v[4*c+0] - f.x;
            const float d1 = v[4*c+1] - f.y;
            const float d2 = v[4*c+2] - f.z;
            const float d3 = v[4*c+3] - f.w;
            s += d0 * d0 + d1 * d1 + d2 * d2 + d3 * d3;
        }
        for (int off = 32; off > 0; off >>= 1) s += __shfl_down(s, off, 64);
        if (t == 0) atomicAdd(&per_batch[b], s);
    }
}

__global__ void finalize_kernel(const float* __restrict__ per_batch, float* __restrict__ out) {
    const int t = threadIdx.x;  // 64 threads
    float v = (t < NBATCH) ? sqrtf(per_batch[t] * (1.0f / (float)NPROJ)) : 0.0f;
    for (int off = 32; off > 0; off >>= 1) v += __shfl_down(v, off, 64);
    if (t == 0) out[0] = v * (1.0f / (float)NBATCH);
}

extern "C" void kernel_launch(void* const* d_in, const int* in_sizes, int n_in,
                              void* d_out, int out_size, void* d_ws, size_t ws_size,
                              hipStream_t stream) {
    const float* x = (const float*)d_in[0];
    const float* y = (const float*)d_in[1];
    const float* theta = (const float*)d_in[2];
    const float* rot = (const float*)d_in[3];
    float* per_batch = (float*)d_ws;
    float* out = (float*)d_out;

    hipMemsetAsync(per_batch, 0, NBATCH * sizeof(float), stream);

    dim3 grid(NPROJ, NBATCH);
    swd_kernel<<<grid, BLK, 0, stream>>>(x, y, theta, rot, per_batch);

    finalize_kernel<<<1, 64, 0, stream>>>(per_batch, out);
}

// Round 14
// 305.139 us; speedup vs baseline: 1.2904x; 1.1609x over previous
//
#include <hip/hip_runtime.h>
#include <math.h>

#define NPTS 4096
#define BLK 128
#define V 64
#define NPROJ 256
#define NBATCH 32

// R20: R13/R19 (verified 330us kernel) + DPP lowering for 14 of 22
// cross-lane stages — attacking the measured 37% idle-issue gap.
// Mechanism: each cross-lane stage is a batch of 64 ds_bpermute/ds_swizzle
// (DS pipe) followed by dependent VALU selects; DS batch (~190cyc) and VALU
// burst (~260cyc) alternate within a wave, VALU idles during every DS batch,
// and 2.5 waves/SIMD can't cover it -> predicts ~60% busy, measured 63%.
// Fix: xor-masks 1,2,3 = quad_perm DPP (0xB1/0x4E/0x1B); mask 7 =
// ROW_HALF_MIRROR (0x141); mask 15 = ROW_MIRROR (0x140) — single VALU-pipe
// ops via __builtin_amdgcn_update_dpp, fully pipelined, no DS involvement.
// Census: rev{1,3,7,15} + stage{1,2}x5 = 14 stages -> DPP; {4,8,16,31,63}
// (8 stages) stay __shfl_xor. Cost +~1408 VALU/wave (mov_dpp where unfused)
// vs removal of ~2/3 of DS alternation stalls.
// Everything else byte-identical to R13/R19 (verified absmax 0.0):
// layout A (idx = lane*64 + reg); merges 2..64 in-reg; merge m>=128:
// rev_shfl<(m-1)>>6> + stage_shfl<j>>6> (j=m/4..64) + stages<32,1>;
// keep() = branchless compare-select; 16 KiB publish buffer;
// waves_per_eu(2,4).

__device__ __forceinline__ void cmpex_asc(float& a, float& b) {
    const float lo = fminf(a, b), hi = fmaxf(a, b);
    a = lo; b = hi;
}

template<int JB, int JL>
__device__ __forceinline__ void stages(float* v) {
#pragma unroll
    for (int r = 0; r < V; ++r)
        if ((r & JB) == 0) cmpex_asc(v[r], v[r | JB]);
    if constexpr (JB > JL) stages<(JB >> 1), JL>(v);
}

template<int MASK>
__device__ __forceinline__ void rev_inreg(float* v) {
    constexpr int S = (MASK + 1) >> 1;
#pragma unroll
    for (int r = 0; r < V; ++r) {
        if ((r & S) == 0) {
            const float a = v[r], b = v[r ^ MASK];
            v[r] = fminf(a, b);
            v[r ^ MASK] = fmaxf(a, b);
        }
    }
}

// Keep-side select: hi lanes keep max, lo lanes keep min, of (mine, q).
__device__ __forceinline__ float keep(float mine, float q, bool hi) {
    return ((q < mine) != hi) ? q : mine;
}

// DPP permute: dst lane gets src lane per CTRL, all rows/banks enabled.
// quad_perm 0xB1 = xor1, 0x4E = xor2, 0x1B = xor3 (within quads; these
// masks never leave a quad). 0x141 = ROW_HALF_MIRROR = xor7 (within 8).
// 0x140 = ROW_MIRROR = xor15 (within 16). VALU pipe, no DS.
template<int CTRL>
__device__ __forceinline__ float dpp_perm(float x) {
    const int i = __float_as_int(x);
    return __int_as_float(__builtin_amdgcn_update_dpp(i, i, CTRL, 0xF, 0xF, true));
}

// Cross-lane xor exchange: DPP where expressible, shfl (DS) otherwise.
template<int XM>
__device__ __forceinline__ float xlane(float x) {
    if constexpr (XM == 1)       return dpp_perm<0xB1>(x);
    else if constexpr (XM == 2)  return dpp_perm<0x4E>(x);
    else if constexpr (XM == 3)  return dpp_perm<0x1B>(x);
    else if constexpr (XM == 7)  return dpp_perm<0x141>(x);
    else if constexpr (XM == 15) return dpp_perm<0x140>(x);
    else return __shfl_xor(x, XM, 64);
}

// Reversal across thread-pair (xor XM), registers reversed (r <-> 63-r).
template<int XM>
__device__ __forceinline__ void rev_shfl(float* v, bool hi) {
#pragma unroll
    for (int r = 0; r < 32; ++r) {
        const float pa = xlane<XM>(v[63 - r]);
        const float pb = xlane<XM>(v[r]);
        v[r]      = keep(v[r],      pa, hi);
        v[63 - r] = keep(v[63 - r], pb, hi);
    }
}
// Same-register cross-thread stage (xor XM).
template<int XM>
__device__ __forceinline__ void stage_shfl(float* v, bool hi) {
#pragma unroll
    for (int r = 0; r < V; ++r) {
        const float q = xlane<XM>(v[r]);
        v[r] = keep(v[r], q, hi);
    }
}

// Natural (own-slot) publish write, float4-slot = (t<<4)|(c^t15)
// (bank-spreading XOR placement: conflict-free, verified 0 since R12).
__device__ __forceinline__ void write_own(float* s, const float* v, int t, int t15) {
    float4* s4 = (float4*)s;
#pragma unroll
    for (int c = 0; c < 16; ++c)
        s4[(t << 4) | (c ^ t15)] =
            make_float4(v[4*c], v[4*c+1], v[4*c+2], v[4*c+3]);
}

__device__ __forceinline__ void load_project(const float* base, float* v,
                                             float p0, float p1, float p2) {
    const float4* b4 = (const float4*)base;
#pragma unroll
    for (int g = 0; g < 16; ++g) {
        float4 a = b4[g * 3 + 0], c = b4[g * 3 + 1], d = b4[g * 3 + 2];
        v[4*g+0] = a.x * p0 + a.y * p1 + a.z * p2;
        v[4*g+1] = a.w * p0 + c.x * p1 + c.y * p2;
        v[4*g+2] = c.z * p0 + c.w * p1 + d.x * p2;
        v[4*g+3] = d.y * p0 + d.z * p1 + d.w * p2;
    }
}

// Full ascending sort of 4096 floats held as v[64] per thread, layout A
// (element idx = t*64 + r). In-register + cross-lane (DPP/DS); no LDS.
__device__ __forceinline__ void sort4096(float* v, int t) {
    const bool hi1  = (t & 1) != 0;
    const bool hi2  = (t & 2) != 0;
    const bool hi4  = (t & 4) != 0;
    const bool hi8  = (t & 8) != 0;
    const bool hi16 = (t & 16) != 0;
    const bool hi32 = (t & 32) != 0;

    // merges 2..64: fully in-register
    rev_inreg<1>(v);
    rev_inreg<3>(v);  stages<1, 1>(v);
    rev_inreg<7>(v);  stages<2, 1>(v);
    rev_inreg<15>(v); stages<4, 1>(v);
    rev_inreg<31>(v); stages<8, 1>(v);
    rev_inreg<63>(v); stages<16, 1>(v);

    // merge 128 (rev: DPP xor1)
    rev_shfl<1>(v, hi1);
    stages<32, 1>(v);

    // merge 256 (rev: DPP xor3; cleaners: DPP xor2, xor1)
    rev_shfl<3>(v, hi2);
    stage_shfl<2>(v, hi2);
    stage_shfl<1>(v, hi1);
    stages<32, 1>(v);

    // merge 512 (rev: DPP xor7)
    rev_shfl<7>(v, hi4);
    stage_shfl<2>(v, hi2);
    stage_shfl<1>(v, hi1);
    stages<32, 1>(v);

    // merge 1024 (rev: DPP xor15; j=256: DS xor4)
    rev_shfl<15>(v, hi8);
    stage_shfl<4>(v, hi4);
    stage_shfl<2>(v, hi2);
    stage_shfl<1>(v, hi1);
    stages<32, 1>(v);

    // merge 2048 (rev: DS xor31; j=512: DS xor8)
    rev_shfl<31>(v, hi16);
    stage_shfl<8>(v, hi8);
    stage_shfl<4>(v, hi4);
    stage_shfl<2>(v, hi2);
    stage_shfl<1>(v, hi1);
    stages<32, 1>(v);

    // merge 4096 (rev: DS xor63; j=1024: DS xor16)
    rev_shfl<63>(v, hi32);
    stage_shfl<16>(v, hi16);
    stage_shfl<8>(v, hi8);
    stage_shfl<4>(v, hi4);
    stage_shfl<2>(v, hi2);
    stage_shfl<1>(v, hi1);
    stages<32, 1>(v);
}

__global__ __launch_bounds__(BLK)
__attribute__((amdgpu_waves_per_eu(2, 4)))
void swd_kernel(
    const float* __restrict__ x, const float* __restrict__ y,
    const float* __restrict__ theta, const float* __restrict__ rot,
    float* __restrict__ per_batch) {
    __shared__ float buf[NPTS];   // 16 KiB — publish buffer only

    const int t = threadIdx.x & 63;       // wave lane
    const int wave = threadIdx.x >> 6;    // 0: x, 1: y
    const int p = blockIdx.x;
    const int b = blockIdx.y;

    const float t0 = theta[p * 3 + 0], t1 = theta[p * 3 + 1], t2 = theta[p * 3 + 2];
    const float* R = rot + b * 9;
    const float p0 = t0 * R[0] + t1 * R[3] + t2 * R[6];
    const float p1 = t0 * R[1] + t1 * R[4] + t2 * R[7];
    const float p2 = t0 * R[2] + t1 * R[5] + t2 * R[8];

    const float* src = wave ? y : x;

    // Each wave sorts its own array, barrier-free.
    float v[V];
    load_project(src + (size_t)b * NPTS * 3 + (size_t)t * V * 3, v, p0, p1, p2);
    sort4096(v, t);

    const int t15 = t & 15;
    // Wave 1 publishes sorted y; wave 0 then diffs.
    if (wave == 1) write_own(buf, v, t, t15);
    __syncthreads();

    if (wave == 0) {
        // Fused read+diff: w never materializes.
        const float4* s4 = (const float4*)buf;
        float s = 0.0f;
#pragma unroll
        for (int c = 0; c < 16; ++c) {
            const float4 f = s4[(t << 4) | (c ^ t15)];
            const float d0 = v[4*c+0] - f.x;
            const float d1 = v[4*c+1] - f.y;
            const float d2 = v[4*c+2] - f.z;
            const float d3 = v[4*c+3] - f.w;
            s += d0 * d0 + d1 * d1 + d2 * d2 + d3 * d3;
        }
        for (int off = 32; off > 0; off >>= 1) s += __shfl_down(s, off, 64);
        if (t == 0) atomicAdd(&per_batch[b], s);
    }
}

__global__ void finalize_kernel(const float* __restrict__ per_batch, float* __restrict__ out) {
    const int t = threadIdx.x;  // 64 threads
    float v = (t < NBATCH) ? sqrtf(per_batch[t] * (1.0f / (float)NPROJ)) : 0.0f;
    for (int off = 32; off > 0; off >>= 1) v += __shfl_down(v, off, 64);
    if (t == 0) out[0] = v * (1.0f / (float)NBATCH);
}

extern "C" void kernel_launch(void* const* d_in, const int* in_sizes, int n_in,
                              void* d_out, int out_size, void* d_ws, size_t ws_size,
                              hipStream_t stream) {
    const float* x = (const float*)d_in[0];
    const float* y = (const float*)d_in[1];
    const float* theta = (const float*)d_in[2];
    const float* rot = (const float*)d_in[3];
    float* per_batch = (float*)d_ws;
    float* out = (float*)d_out;

    hipMemsetAsync(per_batch, 0, NBATCH * sizeof(float), stream);

    dim3 grid(NPROJ, NBATCH);
    swd_kernel<<<grid, BLK, 0, stream>>>(x, y, theta, rot, per_batch);

    finalize_kernel<<<1, 64, 0, stream>>>(per_batch, out);
}

// Round 15
// 301.056 us; speedup vs baseline: 1.3079x; 1.0136x over previous
//
#include <hip/hip_runtime.h>
#include <math.h>

#define NPTS 4096
#define BLK 128
#define V 64
#define NPROJ 256
#define NBATCH 32

// R21: R20 (verified 274us kernel, absmax 0.0) + DPP lowering for masks 4
// and 8 — extending the confirmed DS->VALU pipe-migration mechanism.
// R20 post-mortem: DPP on 14/22 cross-lane stages took 330->274us and
// VALUBusy 63->85%. Remaining idle ~41us; 8 stages still on the DS pipe
// (4 x3, 8 x2, 16, 31, 63).
// New conversions (gfx9 DPP row ops, same __builtin_amdgcn_update_dpp as
// the verified R20 patterns):
//   xor8 = ROW_ROR:8 (0x128): rotate by half a 16-row == xor8. 1-for-1.
//   xor4 = hi4 ? ROW_SHR:4 (0x114, j-4) : ROW_SHL:4 (0x104, j+4) —
//     j^4 = j-4 when j&4 else j+4; both within-row; selector is the
//     stage's existing hi4. 2 DPP + cndmask vs 1 DS.
// DS stages 8 -> 3 (masks 16, 31, 63 have no gfx9-DPP form; permlane16
// variants unverified on gfx950 — not risked).
// Shuttle axis stays closed: 6 structural attempts (occupancy attrs, asm
// pins, sched_barrier, v[32]) all failed to move the arch/acc split;
// instruction accounting says it persists (~17.5K wave-instrs vs ~9.6K
// hand count) but is immovable with available knobs.
// Everything else byte-identical to R20: layout A (idx = lane*64 + reg);
// merges 2..64 in-reg; merge m>=128: rev_shfl<(m-1)>>6> +
// stage_shfl<j>>6> + stages<32,1>; keep() = branchless compare-select;
// 16 KiB publish buffer; waves_per_eu(2,4).

__device__ __forceinline__ void cmpex_asc(float& a, float& b) {
    const float lo = fminf(a, b), hi = fmaxf(a, b);
    a = lo; b = hi;
}

template<int JB, int JL>
__device__ __forceinline__ void stages(float* v) {
#pragma unroll
    for (int r = 0; r < V; ++r)
        if ((r & JB) == 0) cmpex_asc(v[r], v[r | JB]);
    if constexpr (JB > JL) stages<(JB >> 1), JL>(v);
}

template<int MASK>
__device__ __forceinline__ void rev_inreg(float* v) {
    constexpr int S = (MASK + 1) >> 1;
#pragma unroll
    for (int r = 0; r < V; ++r) {
        if ((r & S) == 0) {
            const float a = v[r], b = v[r ^ MASK];
            v[r] = fminf(a, b);
            v[r ^ MASK] = fmaxf(a, b);
        }
    }
}

// Keep-side select: hi lanes keep max, lo lanes keep min, of (mine, q).
__device__ __forceinline__ float keep(float mine, float q, bool hi) {
    return ((q < mine) != hi) ? q : mine;
}

// DPP permute, all rows/banks enabled.
// quad_perm 0xB1=xor1, 0x4E=xor2, 0x1B=xor3; 0x141=ROW_HALF_MIRROR=xor7;
// 0x140=ROW_MIRROR=xor15; 0x128=ROW_ROR:8=xor8 (rotate by half-row);
// 0x114=ROW_SHR:4 (j reads j-4); 0x104=ROW_SHL:4 (j reads j+4).
template<int CTRL>
__device__ __forceinline__ float dpp_perm(float x) {
    const int i = __float_as_int(x);
    return __int_as_float(__builtin_amdgcn_update_dpp(i, i, CTRL, 0xF, 0xF, true));
}

// Cross-lane xor exchange. `hi` is the stage's keep-side bit; for XM==4 it
// equals (t&4), which is exactly the shr/shl selector needed.
template<int XM>
__device__ __forceinline__ float xlane(float x, bool hi) {
    if constexpr (XM == 1)       return dpp_perm<0xB1>(x);
    else if constexpr (XM == 2)  return dpp_perm<0x4E>(x);
    else if constexpr (XM == 3)  return dpp_perm<0x1B>(x);
    else if constexpr (XM == 4)  {
        const float a = dpp_perm<0x104>(x);   // j+4 (for j&4 == 0)
        const float b = dpp_perm<0x114>(x);   // j-4 (for j&4 != 0)
        return hi ? b : a;
    }
    else if constexpr (XM == 7)  return dpp_perm<0x141>(x);
    else if constexpr (XM == 8)  return dpp_perm<0x128>(x);
    else if constexpr (XM == 15) return dpp_perm<0x140>(x);
    else return __shfl_xor(x, XM, 64);
}

// Reversal across thread-pair (xor XM), registers reversed (r <-> 63-r).
template<int XM>
__device__ __forceinline__ void rev_shfl(float* v, bool hi) {
#pragma unroll
    for (int r = 0; r < 32; ++r) {
        const float pa = xlane<XM>(v[63 - r], hi);
        const float pb = xlane<XM>(v[r], hi);
        v[r]      = keep(v[r],      pa, hi);
        v[63 - r] = keep(v[63 - r], pb, hi);
    }
}
// Same-register cross-thread stage (xor XM).
template<int XM>
__device__ __forceinline__ void stage_shfl(float* v, bool hi) {
#pragma unroll
    for (int r = 0; r < V; ++r) {
        const float q = xlane<XM>(v[r], hi);
        v[r] = keep(v[r], q, hi);
    }
}

// Natural (own-slot) publish write, float4-slot = (t<<4)|(c^t15)
// (bank-spreading XOR placement: conflict-free, verified 0 since R12).
__device__ __forceinline__ void write_own(float* s, const float* v, int t, int t15) {
    float4* s4 = (float4*)s;
#pragma unroll
    for (int c = 0; c < 16; ++c)
        s4[(t << 4) | (c ^ t15)] =
            make_float4(v[4*c], v[4*c+1], v[4*c+2], v[4*c+3]);
}

__device__ __forceinline__ void load_project(const float* base, float* v,
                                             float p0, float p1, float p2) {
    const float4* b4 = (const float4*)base;
#pragma unroll
    for (int g = 0; g < 16; ++g) {
        float4 a = b4[g * 3 + 0], c = b4[g * 3 + 1], d = b4[g * 3 + 2];
        v[4*g+0] = a.x * p0 + a.y * p1 + a.z * p2;
        v[4*g+1] = a.w * p0 + c.x * p1 + c.y * p2;
        v[4*g+2] = c.z * p0 + c.w * p1 + d.x * p2;
        v[4*g+3] = d.y * p0 + d.z * p1 + d.w * p2;
    }
}

// Full ascending sort of 4096 floats held as v[64] per thread, layout A
// (element idx = t*64 + r). In-register + cross-lane (DPP/DS); no LDS.
__device__ __forceinline__ void sort4096(float* v, int t) {
    const bool hi1  = (t & 1) != 0;
    const bool hi2  = (t & 2) != 0;
    const bool hi4  = (t & 4) != 0;
    const bool hi8  = (t & 8) != 0;
    const bool hi16 = (t & 16) != 0;
    const bool hi32 = (t & 32) != 0;

    // merges 2..64: fully in-register
    rev_inreg<1>(v);
    rev_inreg<3>(v);  stages<1, 1>(v);
    rev_inreg<7>(v);  stages<2, 1>(v);
    rev_inreg<15>(v); stages<4, 1>(v);
    rev_inreg<31>(v); stages<8, 1>(v);
    rev_inreg<63>(v); stages<16, 1>(v);

    // merge 128 (rev: DPP xor1)
    rev_shfl<1>(v, hi1);
    stages<32, 1>(v);

    // merge 256 (rev: DPP xor3; cleaners: DPP xor2, xor1)
    rev_shfl<3>(v, hi2);
    stage_shfl<2>(v, hi2);
    stage_shfl<1>(v, hi1);
    stages<32, 1>(v);

    // merge 512 (rev: DPP xor7)
    rev_shfl<7>(v, hi4);
    stage_shfl<2>(v, hi2);
    stage_shfl<1>(v, hi1);
    stages<32, 1>(v);

    // merge 1024 (rev: DPP xor15; j=256: DPP xor4 shl/shr pair)
    rev_shfl<15>(v, hi8);
    stage_shfl<4>(v, hi4);
    stage_shfl<2>(v, hi2);
    stage_shfl<1>(v, hi1);
    stages<32, 1>(v);

    // merge 2048 (rev: DS xor31; j=512: DPP xor8 ror; j=256: DPP xor4)
    rev_shfl<31>(v, hi16);
    stage_shfl<8>(v, hi8);
    stage_shfl<4>(v, hi4);
    stage_shfl<2>(v, hi2);
    stage_shfl<1>(v, hi1);
    stages<32, 1>(v);

    // merge 4096 (rev: DS xor63; j=1024: DS xor16; j=512: DPP xor8; ...)
    rev_shfl<63>(v, hi32);
    stage_shfl<16>(v, hi16);
    stage_shfl<8>(v, hi8);
    stage_shfl<4>(v, hi4);
    stage_shfl<2>(v, hi2);
    stage_shfl<1>(v, hi1);
    stages<32, 1>(v);
}

__global__ __launch_bounds__(BLK)
__attribute__((amdgpu_waves_per_eu(2, 4)))
void swd_kernel(
    const float* __restrict__ x, const float* __restrict__ y,
    const float* __restrict__ theta, const float* __restrict__ rot,
    float* __restrict__ per_batch) {
    __shared__ float buf[NPTS];   // 16 KiB — publish buffer only

    const int t = threadIdx.x & 63;       // wave lane
    const int wave = threadIdx.x >> 6;    // 0: x, 1: y
    const int p = blockIdx.x;
    const int b = blockIdx.y;

    const float t0 = theta[p * 3 + 0], t1 = theta[p * 3 + 1], t2 = theta[p * 3 + 2];
    const float* R = rot + b * 9;
    const float p0 = t0 * R[0] + t1 * R[3] + t2 * R[6];
    const float p1 = t0 * R[1] + t1 * R[4] + t2 * R[7];
    const float p2 = t0 * R[2] + t1 * R[5] + t2 * R[8];

    const float* src = wave ? y : x;

    // Each wave sorts its own array, barrier-free.
    float v[V];
    load_project(src + (size_t)b * NPTS * 3 + (size_t)t * V * 3, v, p0, p1, p2);
    sort4096(v, t);

    const int t15 = t & 15;
    // Wave 1 publishes sorted y; wave 0 then diffs.
    if (wave == 1) write_own(buf, v, t, t15);
    __syncthreads();

    if (wave == 0) {
        // Fused read+diff: w never materializes.
        const float4* s4 = (const float4*)buf;
        float s = 0.0f;
#pragma unroll
        for (int c = 0; c < 16; ++c) {
            const float4 f = s4[(t << 4) | (c ^ t15)];
            const float d0 = v[4*c+0] - f.x;
            const float d1 = v[4*c+1] - f.y;
            const float d2 = v[4*c+2] - f.z;
            const float d3 = v[4*c+3] - f.w;
            s += d0 * d0 + d1 * d1 + d2 * d2 + d3 * d3;
        }
        for (int off = 32; off > 0; off >>= 1) s += __shfl_down(s, off, 64);
        if (t == 0) atomicAdd(&per_batch[b], s);
    }
}

__global__ void finalize_kernel(const float* __restrict__ per_batch, float* __restrict__ out) {
    const int t = threadIdx.x;  // 64 threads
    float v = (t < NBATCH) ? sqrtf(per_batch[t] * (1.0f / (float)NPROJ)) : 0.0f;
    for (int off = 32; off > 0; off >>= 1) v += __shfl_down(v, off, 64);
    if (t == 0) out[0] = v * (1.0f / (float)NBATCH);
}

extern "C" void kernel_launch(void* const* d_in, const int* in_sizes, int n_in,
                              void* d_out, int out_size, void* d_ws, size_t ws_size,
                              hipStream_t stream) {
    const float* x = (const float*)d_in[0];
    const float* y = (const float*)d_in[1];
    const float* theta = (const float*)d_in[2];
    const float* rot = (const float*)d_in[3];
    float* per_batch = (float*)d_ws;
    float* out = (float*)d_out;

    hipMemsetAsync(per_batch, 0, NBATCH * sizeof(float), stream);

    dim3 grid(NPROJ, NBATCH);
    swd_kernel<<<grid, BLK, 0, stream>>>(x, y, theta, rot, per_batch);

    finalize_kernel<<<1, 64, 0, stream>>>(per_batch, out);
}